// Round 7
// baseline (402.563 us; speedup 1.0000x reference)
//
#include <hip/hip_runtime.h>
#include <cstdint>
#include <cstddef>

// Problem: L=4, B=8, S=1024, D=256, H=8, DH=32, I=1024, M=4. bf16 MFMA compute.
#define SS 1024
#define DD 256

typedef unsigned short u16;
typedef __bf16 bf16x8 __attribute__((ext_vector_type(8)));
typedef float f32x4 __attribute__((ext_vector_type(4)));
typedef unsigned short us4 __attribute__((ext_vector_type(4)));

typedef __attribute__((address_space(3))) void lds_void_t;
typedef __attribute__((address_space(1))) const void gvoid_t;

__device__ __forceinline__ u16 f2bf(float f) {
  unsigned u = __builtin_bit_cast(unsigned, f);
  u += 0x7fffu + ((u >> 16) & 1u);     // RNE
  return (u16)(u >> 16);
}
__device__ __forceinline__ u16 f2bf_fast(float f) {  // round-half-away, 2 ops
  unsigned u = __builtin_bit_cast(unsigned, f) + 0x8000u;
  return (u16)(u >> 16);
}
__device__ __forceinline__ float bf2f(u16 h) {
  return __builtin_bit_cast(float, ((unsigned)h) << 16);
}
// async global->LDS, 16B per lane; LDS dest must be wave-uniform base + lane*16
__device__ __forceinline__ void gld_lds16(const void* g, void* l) {
  __builtin_amdgcn_global_load_lds((gvoid_t*)g, (lds_void_t*)l, 16, 0, 0);
}
// DPP cross-lane within 16-lane rows (VALU-pipe, avoids LDS-pipe shuffles)
template <int CTRL>
__device__ __forceinline__ float dppf(float x) {
  int i = __builtin_bit_cast(int, x);
  int r = __builtin_amdgcn_update_dpp(i, i, CTRL, 0xf, 0xf, false);
  return __builtin_bit_cast(float, r);
}
__device__ __forceinline__ float row_sum16(float v) {
  v += dppf<0x121>(v);
  v += dppf<0x122>(v);
  v += dppf<0x124>(v);
  v += dppf<0x128>(v);
  return v;
}

// ---------------- weight/bias conversion (fp32 -> bf16, or fp32 copy) -------
struct CvtArgs {
  const float* src[9];
  void* dst[9];
  int n4[9];   // number of float4 elements (multiple of 256)
  int bf[9];   // 1 = convert to bf16, 0 = fp32 copy
};

__global__ __launch_bounds__(256) void cvt_kernel(CvtArgs a) {
  int g = blockIdx.y;
  int i = blockIdx.x * 256 + threadIdx.x;
  if (i >= a.n4[g]) return;                 // block-uniform (n4 % 256 == 0)
  float4 v = ((const float4*)a.src[g])[i];
  if (a.bf[g]) {
    us4 o; o.x = f2bf(v.x); o.y = f2bf(v.y); o.z = f2bf(v.z); o.w = f2bf(v.w);
    ((us4*)a.dst[g])[i] = o;
  } else {
    ((float4*)a.dst[g])[i] = v;
  }
}

// ---------------- embedding: h = emb_w[x] + pe  (bf16 out) ------------------
__global__ __launch_bounds__(256)
void embed_kernel(const int* __restrict__ x, const float* __restrict__ emb,
                  const float* __restrict__ pe, u16* __restrict__ h) {
  int wave = threadIdx.x >> 6, lane = threadIdx.x & 63;
  int row = blockIdx.x * 4 + wave;          // 0..8191
  int s = row & (SS - 1);
  int tok = x[row];
  float4 e = *(const float4*)(emb + (size_t)tok * DD + lane * 4);
  float4 p = *(const float4*)(pe + (size_t)s * DD + lane * 4);
  us4 o; o.x = f2bf(e.x + p.x); o.y = f2bf(e.y + p.y);
  o.z = f2bf(e.z + p.z); o.w = f2bf(e.w + p.w);
  *(us4*)(h + (size_t)row * DD + lane * 4) = o;
}

// ---------------- GEMM: out = A[M,K] @ W[N,K]^T + bias (+epilogue) ----------
enum { EPI_BIAS = 0, EPI_GELU = 1 };

// Q pre-scale: fold (1/sqrt(DH)) * log2(e) into Q so attention scores are
// exp2-ready (allows max-free softmax in attn_kernel).
#define Q_SCALE (0.17677669529663689f * 1.4426950408889634f)

template <int BM, int BN, int EPI, bool QKV>
__global__ __launch_bounds__(256)
void gemm_kernel(const u16* __restrict__ A, const u16* __restrict__ W,
                 const float* __restrict__ bias, void* __restrict__ outp,
                 u16* __restrict__ vt_out, int M, int N, int K) {
  const int n0 = blockIdx.x * BN;
  const int m0 = blockIdx.y * BM;
  const int tid = threadIdx.x;
  const int lane = tid & 63;
  const int l15 = lane & 15;
  const int quad = lane >> 4;
  const int wave = tid >> 6;
  const int wrow = wave >> 1, wcol = wave & 1;
  constexpr int WN = BN / 2;
  constexpr int NT = WN / 16;

  const u16* Wp = W;
  const float* biasp = bias;
  u16* out16 = (u16*)outp;
  int zid = 0;
  if constexpr (QKV) {   // grid.z selects q/k/v: [3][L][D][D] weights, [3][L*D] bias
    zid = blockIdx.z;
    Wp += (size_t)zid * 262144;
    biasp += (size_t)zid * 1024;
    out16 += (size_t)zid * 2097152;
  }

  __shared__ __align__(16) u16 lds[(BM + BN) * 64];
  char* ldsA = (char*)lds;
  char* ldsB = (char*)lds + BM * 128;

  const f32x4 fzero = {0.f, 0.f, 0.f, 0.f};
  f32x4 acc[4][NT];
#pragma unroll
  for (int i = 0; i < 4; ++i)
#pragma unroll
    for (int j = 0; j < NT; ++j) acc[i][j] = fzero;

  for (int kb = 0; kb < K; kb += 64) {
    __syncthreads();
    // stage A tile [BM][64] bf16, chunk (row,slot) <- global chunk slot^(row&7)
#pragma unroll
    for (int r = 0; r < BM * 8 / 256; ++r) {
      int c = r * 256 + tid;
      int row = c >> 3, slot = c & 7;
      int gc = slot ^ (row & 7);
      gld_lds16((const char*)(A + (size_t)(m0 + row) * K + kb) + gc * 16,
                ldsA + c * 16);
    }
#pragma unroll
    for (int r = 0; r < BN * 8 / 256; ++r) {
      int c = r * 256 + tid;
      int row = c >> 3, slot = c & 7;
      int gc = slot ^ (row & 7);
      gld_lds16((const char*)(Wp + (size_t)(n0 + row) * K + kb) + gc * 16,
                ldsB + c * 16);
    }
    __syncthreads();
#pragma unroll
    for (int kk = 0; kk < 2; ++kk) {
      bf16x8 af[4], bfr[NT];
#pragma unroll
      for (int i = 0; i < 4; ++i) {
        int row = wrow * 64 + i * 16 + l15;
        int slot = (kk * 4 + quad) ^ (row & 7);
        af[i] = *(const bf16x8*)(ldsA + row * 128 + slot * 16);
      }
#pragma unroll
      for (int j = 0; j < NT; ++j) {
        int row = wcol * WN + j * 16 + l15;
        int slot = (kk * 4 + quad) ^ (row & 7);
        bfr[j] = *(const bf16x8*)(ldsB + row * 128 + slot * 16);
      }
#pragma unroll
      for (int i = 0; i < 4; ++i)
#pragma unroll
        for (int j = 0; j < NT; ++j)
          acc[i][j] = __builtin_amdgcn_mfma_f32_16x16x32_bf16(af[i], bfr[j],
                                                              acc[i][j], 0, 0, 0);
    }
  }
  // epilogue: C/D layout col=lane&15, row=quad*4+reg
  if (QKV && zid == 2) {
    // V output: write transposed Vt[b][h][d][s] (s contiguous), packed 4 rows
#pragma unroll
    for (int i = 0; i < 4; ++i) {
      int rbase = m0 + wrow * 64 + i * 16 + quad * 4;
      int bidx = rbase >> 10, s0 = rbase & 1023;
#pragma unroll
      for (int j = 0; j < NT; ++j) {
        int col = n0 + wcol * WN + j * 16 + l15;   // = h*32 + d
        float bj = biasp[col];
        us4 o;
        o.x = f2bf(acc[i][j][0] + bj);
        o.y = f2bf(acc[i][j][1] + bj);
        o.z = f2bf(acc[i][j][2] + bj);
        o.w = f2bf(acc[i][j][3] + bj);
        *(us4*)(vt_out + ((size_t)(bidx * 8 + (col >> 5)) * 32 + (col & 31)) * SS + s0) = o;
      }
    }
    return;
  }
  const float oscale = (QKV && zid == 0) ? Q_SCALE : 1.0f;
#pragma unroll
  for (int i = 0; i < 4; ++i) {
    int rbase = m0 + wrow * 64 + i * 16 + quad * 4;
#pragma unroll
    for (int j = 0; j < NT; ++j) {
      int col = n0 + wcol * WN + j * 16 + l15;
      float bj = biasp[col];
#pragma unroll
      for (int r = 0; r < 4; ++r) {
        size_t idx = (size_t)(rbase + r) * N + col;
        float v = acc[i][j][r] + bj;
        if constexpr (EPI == EPI_GELU) {
          v = 0.5f * v * (1.0f + erff(v * 0.70710678118654752f));
          out16[idx] = f2bf(v);
        } else {
          out16[idx] = f2bf(v * oscale);
        }
      }
    }
  }
}

// -------- fused GEMM + bias + residual + LayerNorm (full row, BN=N=256) -----
// BM=32 rows/block, BK=128 (half the barrier phases of BK=64; 72KB LDS).
// 4 waves side-by-side (64 cols each). LN reduction: in-lane + DPP over l15,
// cross-wave via LDS. LAST: logits = LN(h) @ out_w^T + out_b (M=4) fused.
template <int K, bool LAST>
__global__ __launch_bounds__(256)
void gemmln_kernel(const u16* __restrict__ A, const u16* __restrict__ W,
                   const float* __restrict__ bias, const u16* __restrict__ res,
                   const float* __restrict__ g, const float* __restrict__ bta,
                   u16* __restrict__ out, const float* __restrict__ ow,
                   const float* __restrict__ obias, float* __restrict__ outp) {
  const int m0 = blockIdx.x * 32;
  const int tid = threadIdx.x;
  const int l15 = tid & 15;
  const int quad = (tid & 63) >> 4;
  const int wave = tid >> 6;

  __shared__ __align__(16) u16 lds[(32 + 256) * 128];   // 72 KB
  char* ldsA = (char*)lds;                // [32 rows][16 chunks of 16B]
  char* ldsB = (char*)lds + 32 * 256;     // [256 rows][16 chunks of 16B]

  const f32x4 fzero = {0.f, 0.f, 0.f, 0.f};
  f32x4 acc[2][4];
#pragma unroll
  for (int i = 0; i < 2; ++i)
#pragma unroll
    for (int j = 0; j < 4; ++j) acc[i][j] = fzero;

  for (int kb = 0; kb < K; kb += 128) {
    __syncthreads();
#pragma unroll
    for (int r = 0; r < 2; ++r) {      // A: 32 rows x 16 chunks = 512
      int c = r * 256 + tid;
      int row = c >> 4, slot = c & 15;
      int gc = slot ^ (row & 7);
      gld_lds16((const char*)(A + (size_t)(m0 + row) * K + kb) + gc * 16,
                ldsA + c * 16);
    }
#pragma unroll
    for (int r = 0; r < 16; ++r) {     // B: 256 rows x 16 chunks = 4096
      int c = r * 256 + tid;
      int row = c >> 4, slot = c & 15;
      int gc = slot ^ (row & 7);
      gld_lds16((const char*)(W + (size_t)row * K + kb) + gc * 16,
                ldsB + c * 16);
    }
    __syncthreads();
#pragma unroll
    for (int kk = 0; kk < 4; ++kk) {
      bf16x8 af[2], bfr[4];
#pragma unroll
      for (int i = 0; i < 2; ++i) {
        int row = i * 16 + l15;
        int slot = (kk * 4 + quad) ^ (row & 7);
        af[i] = *(const bf16x8*)(ldsA + row * 256 + slot * 16);
      }
#pragma unroll
      for (int j = 0; j < 4; ++j) {
        int row = wave * 64 + j * 16 + l15;
        int slot = (kk * 4 + quad) ^ (row & 7);
        bfr[j] = *(const bf16x8*)(ldsB + row * 256 + slot * 16);
      }
#pragma unroll
      for (int i = 0; i < 2; ++i)
#pragma unroll
        for (int j = 0; j < 4; ++j)
          acc[i][j] = __builtin_amdgcn_mfma_f32_16x16x32_bf16(af[i], bfr[j],
                                                              acc[i][j], 0, 0, 0);
    }
  }
  // bias + residual, per-lane partial LN sums
  float sm[2][4], sq[2][4];
#pragma unroll
  for (int i = 0; i < 2; ++i)
#pragma unroll
    for (int r = 0; r < 4; ++r) { sm[i][r] = 0.f; sq[i][r] = 0.f; }
#pragma unroll
  for (int j = 0; j < 4; ++j) {
    int col = wave * 64 + j * 16 + l15;
    float bj = bias[col];
#pragma unroll
    for (int i = 0; i < 2; ++i) {
#pragma unroll
      for (int r = 0; r < 4; ++r) {
        int grow = m0 + i * 16 + quad * 4 + r;
        float v = acc[i][j][r] + bj + bf2f(res[(size_t)grow * DD + col]);
        acc[i][j][r] = v;
        sm[i][r] += v;
        sq[i][r] += v * v;
      }
    }
  }
#pragma unroll
  for (int i = 0; i < 2; ++i)
#pragma unroll
    for (int r = 0; r < 4; ++r) {
      sm[i][r] = row_sum16(sm[i][r]);
      sq[i][r] = row_sum16(sq[i][r]);
    }
  __syncthreads();                       // staging LDS is dead; reuse for stats
  float* sred = (float*)lds;             // [wave][{sum[32], sumsq[32]}]
  if (l15 == 0) {
#pragma unroll
    for (int i = 0; i < 2; ++i)
#pragma unroll
      for (int r = 0; r < 4; ++r) {
        int ri = i * 16 + quad * 4 + r;
        sred[wave * 64 + ri] = sm[i][r];
        sred[wave * 64 + 32 + ri] = sq[i][r];
      }
  }
  __syncthreads();
  float mean[2][4], rstd[2][4];
#pragma unroll
  for (int i = 0; i < 2; ++i)
#pragma unroll
    for (int r = 0; r < 4; ++r) {
      int ri = i * 16 + quad * 4 + r;
      float S = sred[ri] + sred[64 + ri] + sred[128 + ri] + sred[192 + ri];
      float S2 = sred[32 + ri] + sred[96 + ri] + sred[160 + ri] + sred[224 + ri];
      float mu = S * (1.f / 256.f);
      mean[i][r] = mu;
      rstd[i][r] = rsqrtf(S2 * (1.f / 256.f) - mu * mu + 1e-12f);
    }
  if constexpr (!LAST) {
#pragma unroll
    for (int j = 0; j < 4; ++j) {
      int col = wave * 64 + j * 16 + l15;
      float gj = g[col], bj = bta[col];
#pragma unroll
      for (int i = 0; i < 2; ++i)
#pragma unroll
        for (int r = 0; r < 4; ++r) {
          int grow = m0 + i * 16 + quad * 4 + r;
          float v = (acc[i][j][r] - mean[i][r]) * rstd[i][r] * gj + bj;
          out[(size_t)grow * DD + col] = f2bf(v);
        }
    }
  } else {
    // head fused: logits[row][m] = sum_col LN(h)[row][col] * ow[m][col] + obias[m]
    float lg[2][4][4];
#pragma unroll
    for (int i = 0; i < 2; ++i)
#pragma unroll
      for (int r = 0; r < 4; ++r)
#pragma unroll
        for (int m = 0; m < 4; ++m) lg[i][r][m] = 0.f;
#pragma unroll
    for (int j = 0; j < 4; ++j) {
      int col = wave * 64 + j * 16 + l15;
      float gj = g[col], bj = bta[col];
      float wm[4];
#pragma unroll
      for (int m = 0; m < 4; ++m) wm[m] = ow[m * 256 + col];
#pragma unroll
      for (int i = 0; i < 2; ++i)
#pragma unroll
        for (int r = 0; r < 4; ++r) {
          float v = (acc[i][j][r] - mean[i][r]) * rstd[i][r] * gj + bj;
#pragma unroll
          for (int m = 0; m < 4; ++m) lg[i][r][m] += v * wm[m];
        }
    }
#pragma unroll
    for (int i = 0; i < 2; ++i)
#pragma unroll
      for (int r = 0; r < 4; ++r)
#pragma unroll
        for (int m = 0; m < 4; ++m) lg[i][r][m] = row_sum16(lg[i][r][m]);
    __syncthreads();   // all waves done reading LN stats; reuse lds again
    float* sredh = (float*)lds;
    if (l15 == 0) {
#pragma unroll
      for (int i = 0; i < 2; ++i)
#pragma unroll
        for (int r = 0; r < 4; ++r)
#pragma unroll
          for (int m = 0; m < 4; ++m)
            sredh[wave * 128 + (i * 16 + quad * 4 + r) * 4 + m] = lg[i][r][m];
    }
    __syncthreads();
    if (tid < 128) {
      int rr = tid >> 2, m = tid & 3;
      float s = sredh[rr * 4 + m] + sredh[128 + rr * 4 + m] +
                sredh[256 + rr * 4 + m] + sredh[384 + rr * 4 + m] + obias[m];
      outp[(size_t)(m0 + rr) * 4 + m] = s;
    }
  }
}

// ---------------- flash-style causal attention (max-free softmax) -----------
// 128 q-rows per block (two statically-named Q frags -> no runtime frag
// indexing, R5 lesson). K/V staged once per tile feeds 12 MFMA. One barrier
// per tile. qsel pairing keeps per-CU tile count constant (18).
__global__ __launch_bounds__(256)
void attn_kernel(const u16* __restrict__ Q, const u16* __restrict__ Km,
                 const u16* __restrict__ Vt, u16* __restrict__ ctx) {
  const int tid = threadIdx.x;
  const int l15 = tid & 15;
  const int quad = (tid & 63) >> 4;
  const int wave = tid >> 6;
  const int y = blockIdx.y;
  const int xb = blockIdx.x;                       // 0..7
  const int qsel = ((y >> 5) & 1) ? (7 - xb) : xb; // long+short pairing per CU
  const int q0 = qsel * 128;
  const int b = y >> 3, h = y & 7;

  __shared__ __align__(16) u16 sK[2][64 * 40];    // [key][d] stride 40 u16
  __shared__ __align__(16) u16 sV[2][32 * 72];    // [d][key] stride 72 u16
  __shared__ __align__(16) u16 sP0[4][16 * 72];   // per-wave P, q-half 0
  __shared__ __align__(16) u16 sP1[4][16 * 72];   // per-wave P, q-half 1
  u16* sPw0 = sP0[wave];
  u16* sPw1 = sP1[wave];

  const int qr0 = q0 + wave * 16;        // q rows base, half 0
  const int qr1 = q0 + 64 + wave * 16;   // q rows base, half 1
  bf16x8 qf0 = *(const bf16x8*)(Q + ((size_t)(b * SS + qr0 + l15)) * DD + h * 32 + quad * 8);
  bf16x8 qf1 = *(const bf16x8*)(Q + ((size_t)(b * SS + qr1 + l15)) * DD + h * 32 + quad * 8);

  const int krow = tid >> 2, kch = tid & 3;   // K staging: 64 rows x 4 x 16B
  const int vd = tid >> 3, vch = tid & 7;     // V staging: 32 d x 8 x 16B
  const u16* Kbase = Km + (size_t)(b * SS) * DD + h * 32;
  const u16* Vbase = Vt + ((size_t)y * 32 + vd) * SS;

  uint4 kreg = *(const uint4*)(Kbase + (size_t)krow * DD + kch * 8);
  uint4 vreg = *(const uint4*)(Vbase + vch * 8);

  f32x4 o00 = {0.f, 0.f, 0.f, 0.f}, o01 = {0.f, 0.f, 0.f, 0.f};
  f32x4 o10 = {0.f, 0.f, 0.f, 0.f}, o11 = {0.f, 0.f, 0.f, 0.f};
  const f32x4 fzero = {0.f, 0.f, 0.f, 0.f};
  float rs0[4] = {0.f, 0.f, 0.f, 0.f}, rs1[4] = {0.f, 0.f, 0.f, 0.f};

  const int nt = (q0 >> 6) + 1;   // last tile (diag of q-half 1); diag of half 0 is nt-1
  for (int it = 0; it <= nt; ++it) {
    const int bsel = it & 1;
    *(uint4*)((char*)sK[bsel] + krow * 80 + kch * 16) = kreg;
    *(uint4*)((char*)sV[bsel] + vd * 144 + vch * 16) = vreg;
    if (it < nt) {
      int kb = (it + 1) * 64;
      kreg = *(const uint4*)(Kbase + (size_t)(kb + krow) * DD + kch * 8);
      vreg = *(const uint4*)(Vbase + kb + vch * 8);
    }
    __syncthreads();

    // ---- q-half 0 (rows q0..q0+63): tiles 0..nt-1, diag at nt-1 ----
    if (it < nt) {
      f32x4 s4[4];
#pragma unroll
      for (int t = 0; t < 4; ++t) {
        bf16x8 kf = *(const bf16x8*)((const char*)sK[bsel] + (t * 16 + l15) * 80 + quad * 16);
        s4[t] = __builtin_amdgcn_mfma_f32_16x16x32_bf16(qf0, kf, fzero, 0, 0, 0);
      }
      if (it == nt - 1) {
#pragma unroll
        for (int t = 0; t < 4; ++t) {
          int key = it * 64 + t * 16 + l15;
#pragma unroll
          for (int r = 0; r < 4; ++r) {
            int qr = qr0 + quad * 4 + r;
            float p = exp2f(s4[t][r]);
            p = (key > qr) ? 0.f : p;
            s4[t][r] = p;
            rs0[r] += p;
          }
        }
      } else {
#pragma unroll
        for (int t = 0; t < 4; ++t)
#pragma unroll
          for (int r = 0; r < 4; ++r) {
            float p = exp2f(s4[t][r]);
            s4[t][r] = p;
            rs0[r] += p;
          }
      }
#pragma unroll
      for (int t = 0; t < 4; ++t)
#pragma unroll
        for (int r = 0; r < 4; ++r)
          sPw0[(quad * 4 + r) * 72 + t * 16 + l15] = f2bf_fast(s4[t][r]);
#pragma unroll
      for (int kt = 0; kt < 2; ++kt) {
        bf16x8 pf = *(const bf16x8*)((char*)sPw0 + l15 * 144 + kt * 64 + quad * 16);
        bf16x8 v0 = *(const bf16x8*)((const char*)sV[bsel] + l15 * 144 + kt * 64 + quad * 16);
        bf16x8 v1 = *(const bf16x8*)((const char*)sV[bsel] + (16 + l15) * 144 + kt * 64 + quad * 16);
        o00 = __builtin_amdgcn_mfma_f32_16x16x32_bf16(pf, v0, o00, 0, 0, 0);
        o01 = __builtin_amdgcn_mfma_f32_16x16x32_bf16(pf, v1, o01, 0, 0, 0);
      }
    }
    // ---- q-half 1 (rows q0+64..q0+127): tiles 0..nt, diag at nt ----
    {
      f32x4 s4[4];
#pragma unroll
      for (int t = 0; t < 4; ++t) {
        bf16x8 kf = *(const bf16x8*)((const char*)sK[bsel] + (t * 16 + l15) * 80 + quad * 16);
        s4[t] = __builtin_amdgcn_mfma_f32_16x16x32_bf16(qf1, kf, fzero, 0, 0, 0);
      }
      if (it == nt) {
#pragma unroll
        for (int t = 0; t < 4; ++t) {
          int key = it * 64 + t * 16 + l15;
#pragma unroll
          for (int r = 0; r < 4; ++r) {
            int qr = qr1 + quad * 4 + r;
            float p = exp2f(s4[t][r]);
            p = (key > qr) ? 0.f : p;
            s4[t][r] = p;
            rs1[r] += p;
          }
        }
      } else {
#pragma unroll
        for (int t = 0; t < 4; ++t)
#pragma unroll
          for (int r = 0; r < 4; ++r) {
            float p = exp2f(s4[t][r]);
            s4[t][r] = p;
            rs1[r] += p;
          }
      }
#pragma unroll
      for (int t = 0; t < 4; ++t)
#pragma unroll
        for (int r = 0; r < 4; ++r)
          sPw1[(quad * 4 + r) * 72 + t * 16 + l15] = f2bf_fast(s4[t][r]);
#pragma unroll
      for (int kt = 0; kt < 2; ++kt) {
        bf16x8 pf = *(const bf16x8*)((char*)sPw1 + l15 * 144 + kt * 64 + quad * 16);
        bf16x8 v0 = *(const bf16x8*)((const char*)sV[bsel] + l15 * 144 + kt * 64 + quad * 16);
        bf16x8 v1 = *(const bf16x8*)((const char*)sV[bsel] + (16 + l15) * 144 + kt * 64 + quad * 16);
        o10 = __builtin_amdgcn_mfma_f32_16x16x32_bf16(pf, v0, o10, 0, 0, 0);
        o11 = __builtin_amdgcn_mfma_f32_16x16x32_bf16(pf, v1, o11, 0, 0, 0);
      }
    }
  }
#pragma unroll
  for (int r = 0; r < 4; ++r) {
    float inv0 = 1.0f / row_sum16(rs0[r]);
    float inv1 = 1.0f / row_sum16(rs1[r]);
    int qa = qr0 + quad * 4 + r;
    int qb2 = qr1 + quad * 4 + r;
    size_t base0 = ((size_t)(b * SS + qa)) * DD + h * 32;
    size_t base1 = ((size_t)(b * SS + qb2)) * DD + h * 32;
    ctx[base0 + l15] = f2bf(o00[r] * inv0);
    ctx[base0 + 16 + l15] = f2bf(o01[r] * inv0);
    ctx[base1 + l15] = f2bf(o10[r] * inv1);
    ctx[base1 + 16 + l15] = f2bf(o11[r] * inv1);
  }
}

// ---------------- launcher ---------------------------------------------------
extern "C" void kernel_launch(void* const* d_in, const int* in_sizes, int n_in,
                              void* d_out, int out_size, void* d_ws, size_t ws_size,
                              hipStream_t stream) {
  const int* x = (const int*)d_in[0];
  const float* emb_w = (const float*)d_in[1];
  const float* pe = (const float*)d_in[2];
  const float* q_w = (const float*)d_in[3];
  const float* q_b = (const float*)d_in[4];
  const float* k_w = (const float*)d_in[5];
  const float* k_b = (const float*)d_in[6];
  const float* v_w = (const float*)d_in[7];
  const float* v_b = (const float*)d_in[8];
  const float* o_w = (const float*)d_in[9];
  const float* o_b = (const float*)d_in[10];
  const float* ln1_g = (const float*)d_in[11];
  const float* ln1_b = (const float*)d_in[12];
  const float* f1_w = (const float*)d_in[13];
  const float* f1_b = (const float*)d_in[14];
  const float* f2_w = (const float*)d_in[15];
  const float* f2_b = (const float*)d_in[16];
  const float* ln2_g = (const float*)d_in[17];
  const float* ln2_b = (const float*)d_in[18];
  const float* out_w = (const float*)d_in[19];
  const float* out_b = (const float*)d_in[20];
  float* out = (float*)d_out;

  char* w = (char*)d_ws;
  const size_t MB = 1ull << 20;
  u16* hb    = (u16*)(w + 0 * MB);    // [8192,256] bf16
  u16* qb    = (u16*)(w + 4 * MB);
  u16* kbuf  = (u16*)(w + 8 * MB);
  u16* vtb   = (u16*)(w + 12 * MB);   // V transposed [64 bh][32 d][1024 s]
  u16* ctxb  = (u16*)(w + 16 * MB);
  u16* attnb = (u16*)(w + 20 * MB);
  u16* ffb   = (u16*)(w + 24 * MB);   // [8192,1024] bf16
  u16* wqkv  = (u16*)(w + 48 * MB);   // [3][L,256,256] bf16
  u16* wo    = (u16*)(w + 50 * MB);   // [L,256,256] bf16
  u16* wf1   = (u16*)(w + 51 * MB);   // [L,1024,256] bf16
  u16* wf2   = (u16*)(w + 53 * MB);   // [L,256,1024] bf16
  float* bqkv = (float*)(w + 55 * MB); // [3][L*256] f32

  CvtArgs ca;
  ca.src[0] = q_w;  ca.dst[0] = wqkv;            ca.n4[0] = 65536;  ca.bf[0] = 1;
  ca.src[1] = k_w;  ca.dst[1] = wqkv + 262144;   ca.n4[1] = 65536;  ca.bf[1] = 1;
  ca.src[2] = v_w;  ca.dst[2] = wqkv + 524288;   ca.n4[2] = 65536;  ca.bf[2] = 1;
  ca.src[3] = o_w;  ca.dst[3] = wo;              ca.n4[3] = 65536;  ca.bf[3] = 1;
  ca.src[4] = f1_w; ca.dst[4] = wf1;             ca.n4[4] = 262144; ca.bf[4] = 1;
  ca.src[5] = f2_w; ca.dst[5] = wf2;             ca.n4[5] = 262144; ca.bf[5] = 1;
  ca.src[6] = q_b;  ca.dst[6] = bqkv;            ca.n4[6] = 256;    ca.bf[6] = 0;
  ca.src[7] = k_b;  ca.dst[7] = bqkv + 1024;     ca.n4[7] = 256;    ca.bf[7] = 0;
  ca.src[8] = v_b;  ca.dst[8] = bqkv + 2048;     ca.n4[8] = 256;    ca.bf[8] = 0;
  cvt_kernel<<<dim3(1024, 9), 256, 0, stream>>>(ca);

  embed_kernel<<<2048, 256, 0, stream>>>(x, emb_w, pe, hb);

  for (int l = 0; l < 4; ++l) {
    const size_t wofs = (size_t)l * 65536;   // D*D per layer
    const size_t fofs = (size_t)l * 262144;  // I*D per layer
    // fused QKV (grid.z picks q/k/v; z==0 scales Q; z==2 writes V transposed)
    gemm_kernel<128, 64, EPI_BIAS, true><<<dim3(4, 64, 3), 256, 0, stream>>>(
        hb, wqkv + wofs, bqkv + l * 256, qb, vtb, 8192, 256, 256);
    attn_kernel<<<dim3(8, 64), 256, 0, stream>>>(qb, kbuf, vtb, ctxb);
    // fused O-proj + residual(hb) + LN1 -> attnb
    gemmln_kernel<256, false><<<256, 256, 0, stream>>>(
        ctxb, wo + wofs, o_b + l * 256, hb, ln1_g + l * 256, ln1_b + l * 256,
        attnb, nullptr, nullptr, nullptr);
    gemm_kernel<128, 128, EPI_GELU, false><<<dim3(8, 64), 256, 0, stream>>>(
        attnb, wf1 + fofs, f1_b + l * 1024, ffb, nullptr, 8192, 1024, 256);
    // fused FFN2 + residual(attnb) + LN2 -> hb (last layer: + head -> out)
    if (l < 3) {
      gemmln_kernel<1024, false><<<256, 256, 0, stream>>>(
          ffb, wf2 + fofs, f2_b + l * 256, attnb, ln2_g + l * 256,
          ln2_b + l * 256, hb, nullptr, nullptr, nullptr);
    } else {
      gemmln_kernel<1024, true><<<256, 256, 0, stream>>>(
          ffb, wf2 + fofs, f2_b + l * 256, attnb, ln2_g + l * 256,
          ln2_b + l * 256, hb, out_w, out_b, out);
    }
  }
}

// Round 8
// 381.307 us; speedup vs baseline: 1.0557x; 1.0557x over previous
//
#include <hip/hip_runtime.h>
#include <cstdint>
#include <cstddef>

// Problem: L=4, B=8, S=1024, D=256, H=8, DH=32, I=1024, M=4. bf16 MFMA compute.
#define SS 1024
#define DD 256

typedef unsigned short u16;
typedef __bf16 bf16x8 __attribute__((ext_vector_type(8)));
typedef float f32x4 __attribute__((ext_vector_type(4)));
typedef unsigned short us4 __attribute__((ext_vector_type(4)));

typedef __attribute__((address_space(3))) void lds_void_t;
typedef __attribute__((address_space(1))) const void gvoid_t;

__device__ __forceinline__ u16 f2bf(float f) {
  unsigned u = __builtin_bit_cast(unsigned, f);
  u += 0x7fffu + ((u >> 16) & 1u);     // RNE
  return (u16)(u >> 16);
}
__device__ __forceinline__ u16 f2bf_fast(float f) {  // round-half-away, 2 ops
  unsigned u = __builtin_bit_cast(unsigned, f) + 0x8000u;
  return (u16)(u >> 16);
}
__device__ __forceinline__ float bf2f(u16 h) {
  return __builtin_bit_cast(float, ((unsigned)h) << 16);
}
// async global->LDS, 16B per lane; LDS dest must be wave-uniform base + lane*16
__device__ __forceinline__ void gld_lds16(const void* g, void* l) {
  __builtin_amdgcn_global_load_lds((gvoid_t*)g, (lds_void_t*)l, 16, 0, 0);
}
// DPP cross-lane within 16-lane rows (VALU-pipe, avoids LDS-pipe shuffles)
template <int CTRL>
__device__ __forceinline__ float dppf(float x) {
  int i = __builtin_bit_cast(int, x);
  int r = __builtin_amdgcn_update_dpp(i, i, CTRL, 0xf, 0xf, false);
  return __builtin_bit_cast(float, r);
}
__device__ __forceinline__ float row_sum16(float v) {
  v += dppf<0x121>(v);
  v += dppf<0x122>(v);
  v += dppf<0x124>(v);
  v += dppf<0x128>(v);
  return v;
}
// tanh-form GELU (R4-validated: passed at absmax 0.0078): exp2-domain tanh
__device__ __forceinline__ float gelu_f(float x) {
  float x2 = x * x;
  float y = x * (0.7978845608028654f + 0.0356774081363f * x2);
  float e = exp2f(fminf(-2.8853900817779268f * y, 88.f));  // exp(-2y)
  float th = (1.f - e) * __builtin_amdgcn_rcpf(1.f + e);
  return 0.5f * x * (1.f + th);
}

// ---------------- weight/bias conversion (fp32 -> bf16, or fp32 copy) -------
struct CvtArgs {
  const float* src[9];
  void* dst[9];
  int n4[9];   // number of float4 elements (multiple of 256)
  int bf[9];   // 1 = convert to bf16, 0 = fp32 copy
};

__global__ __launch_bounds__(256) void cvt_kernel(CvtArgs a) {
  int g = blockIdx.y;
  int i = blockIdx.x * 256 + threadIdx.x;
  if (i >= a.n4[g]) return;                 // block-uniform (n4 % 256 == 0)
  float4 v = ((const float4*)a.src[g])[i];
  if (a.bf[g]) {
    us4 o; o.x = f2bf(v.x); o.y = f2bf(v.y); o.z = f2bf(v.z); o.w = f2bf(v.w);
    ((us4*)a.dst[g])[i] = o;
  } else {
    ((float4*)a.dst[g])[i] = v;
  }
}

// ---------------- embedding: h = emb_w[x] + pe  (bf16 out) ------------------
__global__ __launch_bounds__(256)
void embed_kernel(const int* __restrict__ x, const float* __restrict__ emb,
                  const float* __restrict__ pe, u16* __restrict__ h) {
  int wave = threadIdx.x >> 6, lane = threadIdx.x & 63;
  int row = blockIdx.x * 4 + wave;          // 0..8191
  int s = row & (SS - 1);
  int tok = x[row];
  float4 e = *(const float4*)(emb + (size_t)tok * DD + lane * 4);
  float4 p = *(const float4*)(pe + (size_t)s * DD + lane * 4);
  us4 o; o.x = f2bf(e.x + p.x); o.y = f2bf(e.y + p.y);
  o.z = f2bf(e.z + p.z); o.w = f2bf(e.w + p.w);
  *(us4*)(h + (size_t)row * DD + lane * 4) = o;
}

// ---------------- GEMM: out = A[M,K] @ W[N,K]^T + bias (+epilogue) ----------
enum { EPI_BIAS = 0, EPI_GELU = 1 };

// Q pre-scale: fold (1/sqrt(DH)) * log2(e) into Q so attention scores are
// exp2-ready (allows max-free softmax in attn_kernel).
#define Q_SCALE (0.17677669529663689f * 1.4426950408889634f)

template <int BM, int BN, int EPI, bool QKV>
__global__ __launch_bounds__(256)
void gemm_kernel(const u16* __restrict__ A, const u16* __restrict__ W,
                 const float* __restrict__ bias, void* __restrict__ outp,
                 u16* __restrict__ vt_out, int M, int N, int K) {
  const int n0 = blockIdx.x * BN;
  const int m0 = blockIdx.y * BM;
  const int tid = threadIdx.x;
  const int lane = tid & 63;
  const int l15 = lane & 15;
  const int quad = lane >> 4;
  const int wave = tid >> 6;
  const int wrow = wave >> 1, wcol = wave & 1;
  constexpr int WN = BN / 2;
  constexpr int NT = WN / 16;

  const u16* Wp = W;
  const float* biasp = bias;
  u16* out16 = (u16*)outp;
  int zid = 0;
  if constexpr (QKV) {   // grid.z selects q/k/v: [3][L][D][D] weights, [3][L*D] bias
    zid = blockIdx.z;
    Wp += (size_t)zid * 262144;
    biasp += (size_t)zid * 1024;
    out16 += (size_t)zid * 2097152;
  }

  __shared__ __align__(16) u16 lds[(BM + BN) * 64];
  char* ldsA = (char*)lds;
  char* ldsB = (char*)lds + BM * 128;

  const f32x4 fzero = {0.f, 0.f, 0.f, 0.f};
  f32x4 acc[4][NT];
#pragma unroll
  for (int i = 0; i < 4; ++i)
#pragma unroll
    for (int j = 0; j < NT; ++j) acc[i][j] = fzero;

  for (int kb = 0; kb < K; kb += 64) {
    __syncthreads();
    // stage A tile [BM][64] bf16, chunk (row,slot) <- global chunk slot^(row&7)
#pragma unroll
    for (int r = 0; r < BM * 8 / 256; ++r) {
      int c = r * 256 + tid;
      int row = c >> 3, slot = c & 7;
      int gc = slot ^ (row & 7);
      gld_lds16((const char*)(A + (size_t)(m0 + row) * K + kb) + gc * 16,
                ldsA + c * 16);
    }
#pragma unroll
    for (int r = 0; r < BN * 8 / 256; ++r) {
      int c = r * 256 + tid;
      int row = c >> 3, slot = c & 7;
      int gc = slot ^ (row & 7);
      gld_lds16((const char*)(Wp + (size_t)(n0 + row) * K + kb) + gc * 16,
                ldsB + c * 16);
    }
    __syncthreads();
#pragma unroll
    for (int kk = 0; kk < 2; ++kk) {
      bf16x8 af[4], bfr[NT];
#pragma unroll
      for (int i = 0; i < 4; ++i) {
        int row = wrow * 64 + i * 16 + l15;
        int slot = (kk * 4 + quad) ^ (row & 7);
        af[i] = *(const bf16x8*)(ldsA + row * 128 + slot * 16);
      }
#pragma unroll
      for (int j = 0; j < NT; ++j) {
        int row = wcol * WN + j * 16 + l15;
        int slot = (kk * 4 + quad) ^ (row & 7);
        bfr[j] = *(const bf16x8*)(ldsB + row * 128 + slot * 16);
      }
#pragma unroll
      for (int i = 0; i < 4; ++i)
#pragma unroll
        for (int j = 0; j < NT; ++j)
          acc[i][j] = __builtin_amdgcn_mfma_f32_16x16x32_bf16(af[i], bfr[j],
                                                              acc[i][j], 0, 0, 0);
    }
  }
  // epilogue: C/D layout col=lane&15, row=quad*4+reg
  if (QKV && zid == 2) {
    // V output: write transposed Vt[b][h][d][s] (s contiguous), packed 4 rows
#pragma unroll
    for (int i = 0; i < 4; ++i) {
      int rbase = m0 + wrow * 64 + i * 16 + quad * 4;
      int bidx = rbase >> 10, s0 = rbase & 1023;
#pragma unroll
      for (int j = 0; j < NT; ++j) {
        int col = n0 + wcol * WN + j * 16 + l15;   // = h*32 + d
        float bj = biasp[col];
        us4 o;
        o.x = f2bf(acc[i][j][0] + bj);
        o.y = f2bf(acc[i][j][1] + bj);
        o.z = f2bf(acc[i][j][2] + bj);
        o.w = f2bf(acc[i][j][3] + bj);
        *(us4*)(vt_out + ((size_t)(bidx * 8 + (col >> 5)) * 32 + (col & 31)) * SS + s0) = o;
      }
    }
    return;
  }
  const float oscale = (QKV && zid == 0) ? Q_SCALE : 1.0f;
#pragma unroll
  for (int i = 0; i < 4; ++i) {
    int rbase = m0 + wrow * 64 + i * 16 + quad * 4;
#pragma unroll
    for (int j = 0; j < NT; ++j) {
      int col = n0 + wcol * WN + j * 16 + l15;
      float bj = biasp[col];
#pragma unroll
      for (int r = 0; r < 4; ++r) {
        size_t idx = (size_t)(rbase + r) * N + col;
        float v = acc[i][j][r] + bj;
        if constexpr (EPI == EPI_GELU) {
          out16[idx] = f2bf(gelu_f(v));
        } else {
          out16[idx] = f2bf(v * oscale);
        }
      }
    }
  }
}

// -------- fused GEMM + bias + residual + LayerNorm (full row, BN=N=256) -----
// BM=16 rows/block, grid 512 -> 2 blocks/CU so barrier drains of one block
// are hidden by the sibling (m114 lesson; R7's BK=128 at 1 block/CU failed).
// 4 waves side-by-side (64 cols each). LN: in-lane + DPP over l15, cross-wave
// via LDS. LAST: logits = LN(h) @ out_w^T + out_b (M=4) fused.
template <int K, bool LAST>
__global__ __launch_bounds__(256)
void gemmln_kernel(const u16* __restrict__ A, const u16* __restrict__ W,
                   const float* __restrict__ bias, const u16* __restrict__ res,
                   const float* __restrict__ g, const float* __restrict__ bta,
                   u16* __restrict__ out, const float* __restrict__ ow,
                   const float* __restrict__ obias, float* __restrict__ outp) {
  const int m0 = blockIdx.x * 16;
  const int tid = threadIdx.x;
  const int l15 = tid & 15;
  const int quad = (tid & 63) >> 4;
  const int wave = tid >> 6;

  __shared__ __align__(16) u16 lds[(16 + 256) * 64];   // 34 KB -> 4 blocks/CU by LDS
  char* ldsA = (char*)lds;
  char* ldsB = (char*)lds + 16 * 128;

  const f32x4 fzero = {0.f, 0.f, 0.f, 0.f};
  f32x4 acc[4];
#pragma unroll
  for (int j = 0; j < 4; ++j) acc[j] = fzero;

  for (int kb = 0; kb < K; kb += 64) {
    __syncthreads();
    if (tid < 128) {                   // A: 16 rows x 8 chunks = 128 (waves 0,1)
      int c = tid;
      int row = c >> 3, slot = c & 7;
      int gc = slot ^ (row & 7);
      gld_lds16((const char*)(A + (size_t)(m0 + row) * K + kb) + gc * 16,
                ldsA + c * 16);
    }
#pragma unroll
    for (int r = 0; r < 8; ++r) {      // B: 256 rows x 8 chunks = 2048
      int c = r * 256 + tid;
      int row = c >> 3, slot = c & 7;
      int gc = slot ^ (row & 7);
      gld_lds16((const char*)(W + (size_t)row * K + kb) + gc * 16,
                ldsB + c * 16);
    }
    __syncthreads();
#pragma unroll
    for (int kk = 0; kk < 2; ++kk) {
      bf16x8 af, bfr[4];
      {
        int row = l15;
        int slot = (kk * 4 + quad) ^ (row & 7);
        af = *(const bf16x8*)(ldsA + row * 128 + slot * 16);
      }
#pragma unroll
      for (int j = 0; j < 4; ++j) {
        int row = wave * 64 + j * 16 + l15;
        int slot = (kk * 4 + quad) ^ (row & 7);
        bfr[j] = *(const bf16x8*)(ldsB + row * 128 + slot * 16);
      }
#pragma unroll
      for (int j = 0; j < 4; ++j)
        acc[j] = __builtin_amdgcn_mfma_f32_16x16x32_bf16(af, bfr[j], acc[j], 0, 0, 0);
    }
  }
  // bias + residual, per-lane partial LN sums
  float sm[4], sq[4];
#pragma unroll
  for (int r = 0; r < 4; ++r) { sm[r] = 0.f; sq[r] = 0.f; }
#pragma unroll
  for (int j = 0; j < 4; ++j) {
    int col = wave * 64 + j * 16 + l15;
    float bj = bias[col];
#pragma unroll
    for (int r = 0; r < 4; ++r) {
      int grow = m0 + quad * 4 + r;
      float v = acc[j][r] + bj + bf2f(res[(size_t)grow * DD + col]);
      acc[j][r] = v;
      sm[r] += v;
      sq[r] += v * v;
    }
  }
#pragma unroll
  for (int r = 0; r < 4; ++r) {
    sm[r] = row_sum16(sm[r]);
    sq[r] = row_sum16(sq[r]);
  }
  __syncthreads();                       // staging LDS is dead; reuse for stats
  float* sred = (float*)lds;             // [wave][{sum[16], sumsq[16]}]
  if (l15 == 0) {
#pragma unroll
    for (int r = 0; r < 4; ++r) {
      int ri = quad * 4 + r;
      sred[wave * 32 + ri] = sm[r];
      sred[wave * 32 + 16 + ri] = sq[r];
    }
  }
  __syncthreads();
  float mean[4], rstd[4];
#pragma unroll
  for (int r = 0; r < 4; ++r) {
    int ri = quad * 4 + r;
    float S = sred[ri] + sred[32 + ri] + sred[64 + ri] + sred[96 + ri];
    float S2 = sred[16 + ri] + sred[48 + ri] + sred[80 + ri] + sred[112 + ri];
    float mu = S * (1.f / 256.f);
    mean[r] = mu;
    rstd[r] = rsqrtf(S2 * (1.f / 256.f) - mu * mu + 1e-12f);
  }
  if constexpr (!LAST) {
#pragma unroll
    for (int j = 0; j < 4; ++j) {
      int col = wave * 64 + j * 16 + l15;
      float gj = g[col], bj = bta[col];
#pragma unroll
      for (int r = 0; r < 4; ++r) {
        int grow = m0 + quad * 4 + r;
        float v = (acc[j][r] - mean[r]) * rstd[r] * gj + bj;
        out[(size_t)grow * DD + col] = f2bf(v);
      }
    }
  } else {
    // head fused: logits[row][m] = sum_col LN(h)[row][col] * ow[m][col] + obias[m]
    float lg[4][4];
#pragma unroll
    for (int r = 0; r < 4; ++r)
#pragma unroll
      for (int m = 0; m < 4; ++m) lg[r][m] = 0.f;
#pragma unroll
    for (int j = 0; j < 4; ++j) {
      int col = wave * 64 + j * 16 + l15;
      float gj = g[col], bj = bta[col];
      float wm[4];
#pragma unroll
      for (int m = 0; m < 4; ++m) wm[m] = ow[m * 256 + col];
#pragma unroll
      for (int r = 0; r < 4; ++r) {
        float v = (acc[j][r] - mean[r]) * rstd[r] * gj + bj;
#pragma unroll
        for (int m = 0; m < 4; ++m) lg[r][m] += v * wm[m];
      }
    }
#pragma unroll
    for (int r = 0; r < 4; ++r)
#pragma unroll
      for (int m = 0; m < 4; ++m) lg[r][m] = row_sum16(lg[r][m]);
    __syncthreads();   // all waves done reading LN stats; reuse lds again
    float* sredh = (float*)lds;
    if (l15 == 0) {
#pragma unroll
      for (int r = 0; r < 4; ++r)
#pragma unroll
        for (int m = 0; m < 4; ++m)
          sredh[wave * 64 + (quad * 4 + r) * 4 + m] = lg[r][m];
    }
    __syncthreads();
    if (tid < 64) {
      int rr = tid >> 2, m = tid & 3;
      float s = sredh[rr * 4 + m] + sredh[64 + rr * 4 + m] +
                sredh[128 + rr * 4 + m] + sredh[192 + rr * 4 + m] + obias[m];
      outp[(size_t)(m0 + rr) * 4 + m] = s;
    }
  }
}

// ---------------- flash-style causal attention (max-free softmax) -----------
// LDS-staged K/V with ping-pong buffers, ONE barrier per k-tile (R3/R6-verified
// structure). Scores arrive exp2-ready (Q pre-scaled). R5 lesson: no
// runtime-indexed register frag arrays (-> scratch).
__global__ __launch_bounds__(256)
void attn_kernel(const u16* __restrict__ Q, const u16* __restrict__ Km,
                 const u16* __restrict__ Vt, u16* __restrict__ ctx) {
  const int tid = threadIdx.x;
  const int l15 = tid & 15;
  const int quad = (tid & 63) >> 4;
  const int wave = tid >> 6;
  const int y = blockIdx.y;
  const int qt = 15 - (((int)blockIdx.x + ((y >> 4) << 2)) & 15);  // long-first, CU-balanced
  const int q0 = qt * 64;
  const int b = y >> 3, h = y & 7;
  const int q0w = q0 + wave * 16;

  __shared__ __align__(16) u16 sK[2][64 * 40];   // [key][d] stride 40 u16
  __shared__ __align__(16) u16 sV[2][32 * 72];   // [d][key] stride 72 u16
  __shared__ __align__(16) u16 sP[4][16 * 72];   // per-wave [q][key]
  u16* sPw = sP[wave];

  bf16x8 qf = *(const bf16x8*)(Q + ((size_t)(b * SS + q0w + l15)) * DD + h * 32 + quad * 8);

  const int krow = tid >> 2, kch = tid & 3;   // K staging: 64 rows x 4 x 16B
  const int vd = tid >> 3, vch = tid & 7;     // V staging: 32 d x 8 x 16B
  const u16* Kbase = Km + (size_t)(b * SS) * DD + h * 32;
  const u16* Vbase = Vt + ((size_t)y * 32 + vd) * SS;

  uint4 kreg = *(const uint4*)(Kbase + (size_t)krow * DD + kch * 8);
  uint4 vreg = *(const uint4*)(Vbase + vch * 8);

  f32x4 o0 = {0.f, 0.f, 0.f, 0.f}, o1 = {0.f, 0.f, 0.f, 0.f};
  const f32x4 fzero = {0.f, 0.f, 0.f, 0.f};
  float rs[4] = {0.f, 0.f, 0.f, 0.f};

  const int nt = q0 >> 6;
  for (int it = 0; it <= nt; ++it) {
    const int bsel = it & 1;
    *(uint4*)((char*)sK[bsel] + krow * 80 + kch * 16) = kreg;
    *(uint4*)((char*)sV[bsel] + vd * 144 + vch * 16) = vreg;
    if (it < nt) {
      int kb = (it + 1) * 64;
      kreg = *(const uint4*)(Kbase + (size_t)(kb + krow) * DD + kch * 8);
      vreg = *(const uint4*)(Vbase + kb + vch * 8);
    }
    __syncthreads();

    f32x4 s4[4];
#pragma unroll
    for (int t = 0; t < 4; ++t) {
      bf16x8 kf = *(const bf16x8*)((const char*)sK[bsel] + (t * 16 + l15) * 80 + quad * 16);
      s4[t] = __builtin_amdgcn_mfma_f32_16x16x32_bf16(qf, kf, fzero, 0, 0, 0);
    }
    if (it == nt) {          // only the diagonal tile needs causal masking
#pragma unroll
      for (int t = 0; t < 4; ++t) {
        int key = it * 64 + t * 16 + l15;
#pragma unroll
        for (int r = 0; r < 4; ++r) {
          int qr = q0w + quad * 4 + r;
          float p = exp2f(s4[t][r]);
          p = (key > qr) ? 0.f : p;
          s4[t][r] = p;
          rs[r] += p;
        }
      }
    } else {
#pragma unroll
      for (int t = 0; t < 4; ++t)
#pragma unroll
        for (int r = 0; r < 4; ++r) {
          float p = exp2f(s4[t][r]);
          s4[t][r] = p;
          rs[r] += p;
        }
    }
#pragma unroll
    for (int t = 0; t < 4; ++t)
#pragma unroll
      for (int r = 0; r < 4; ++r)
        sPw[(quad * 4 + r) * 72 + t * 16 + l15] = f2bf_fast(s4[t][r]);
#pragma unroll
    for (int kt = 0; kt < 2; ++kt) {
      bf16x8 pf = *(const bf16x8*)((char*)sPw + l15 * 144 + kt * 64 + quad * 16);
      bf16x8 v0 = *(const bf16x8*)((const char*)sV[bsel] + l15 * 144 + kt * 64 + quad * 16);
      bf16x8 v1 = *(const bf16x8*)((const char*)sV[bsel] + (16 + l15) * 144 + kt * 64 + quad * 16);
      o0 = __builtin_amdgcn_mfma_f32_16x16x32_bf16(pf, v0, o0, 0, 0, 0);
      o1 = __builtin_amdgcn_mfma_f32_16x16x32_bf16(pf, v1, o1, 0, 0, 0);
    }
  }
#pragma unroll
  for (int r = 0; r < 4; ++r) {
    float inv = 1.0f / row_sum16(rs[r]);
    int q = q0w + quad * 4 + r;
    size_t base = ((size_t)(b * SS + q)) * DD + h * 32;
    ctx[base + l15] = f2bf(o0[r] * inv);
    ctx[base + 16 + l15] = f2bf(o1[r] * inv);
  }
}

// ---------------- launcher ---------------------------------------------------
extern "C" void kernel_launch(void* const* d_in, const int* in_sizes, int n_in,
                              void* d_out, int out_size, void* d_ws, size_t ws_size,
                              hipStream_t stream) {
  const int* x = (const int*)d_in[0];
  const float* emb_w = (const float*)d_in[1];
  const float* pe = (const float*)d_in[2];
  const float* q_w = (const float*)d_in[3];
  const float* q_b = (const float*)d_in[4];
  const float* k_w = (const float*)d_in[5];
  const float* k_b = (const float*)d_in[6];
  const float* v_w = (const float*)d_in[7];
  const float* v_b = (const float*)d_in[8];
  const float* o_w = (const float*)d_in[9];
  const float* o_b = (const float*)d_in[10];
  const float* ln1_g = (const float*)d_in[11];
  const float* ln1_b = (const float*)d_in[12];
  const float* f1_w = (const float*)d_in[13];
  const float* f1_b = (const float*)d_in[14];
  const float* f2_w = (const float*)d_in[15];
  const float* f2_b = (const float*)d_in[16];
  const float* ln2_g = (const float*)d_in[17];
  const float* ln2_b = (const float*)d_in[18];
  const float* out_w = (const float*)d_in[19];
  const float* out_b = (const float*)d_in[20];
  float* out = (float*)d_out;

  char* w = (char*)d_ws;
  const size_t MB = 1ull << 20;
  u16* hb    = (u16*)(w + 0 * MB);    // [8192,256] bf16
  u16* qb    = (u16*)(w + 4 * MB);
  u16* kbuf  = (u16*)(w + 8 * MB);
  u16* vtb   = (u16*)(w + 12 * MB);   // V transposed [64 bh][32 d][1024 s]
  u16* ctxb  = (u16*)(w + 16 * MB);
  u16* attnb = (u16*)(w + 20 * MB);
  u16* ffb   = (u16*)(w + 24 * MB);   // [8192,1024] bf16
  u16* wqkv  = (u16*)(w + 48 * MB);   // [3][L,256,256] bf16
  u16* wo    = (u16*)(w + 50 * MB);   // [L,256,256] bf16
  u16* wf1   = (u16*)(w + 51 * MB);   // [L,1024,256] bf16
  u16* wf2   = (u16*)(w + 53 * MB);   // [L,256,1024] bf16
  float* bqkv = (float*)(w + 55 * MB); // [3][L*256] f32

  CvtArgs ca;
  ca.src[0] = q_w;  ca.dst[0] = wqkv;            ca.n4[0] = 65536;  ca.bf[0] = 1;
  ca.src[1] = k_w;  ca.dst[1] = wqkv + 262144;   ca.n4[1] = 65536;  ca.bf[1] = 1;
  ca.src[2] = v_w;  ca.dst[2] = wqkv + 524288;   ca.n4[2] = 65536;  ca.bf[2] = 1;
  ca.src[3] = o_w;  ca.dst[3] = wo;              ca.n4[3] = 65536;  ca.bf[3] = 1;
  ca.src[4] = f1_w; ca.dst[4] = wf1;             ca.n4[4] = 262144; ca.bf[4] = 1;
  ca.src[5] = f2_w; ca.dst[5] = wf2;             ca.n4[5] = 262144; ca.bf[5] = 1;
  ca.src[6] = q_b;  ca.dst[6] = bqkv;            ca.n4[6] = 256;    ca.bf[6] = 0;
  ca.src[7] = k_b;  ca.dst[7] = bqkv + 1024;     ca.n4[7] = 256;    ca.bf[7] = 0;
  ca.src[8] = v_b;  ca.dst[8] = bqkv + 2048;     ca.n4[8] = 256;    ca.bf[8] = 0;
  cvt_kernel<<<dim3(1024, 9), 256, 0, stream>>>(ca);

  embed_kernel<<<2048, 256, 0, stream>>>(x, emb_w, pe, hb);

  for (int l = 0; l < 4; ++l) {
    const size_t wofs = (size_t)l * 65536;   // D*D per layer
    const size_t fofs = (size_t)l * 262144;  // I*D per layer
    // fused QKV (grid.z picks q/k/v; z==0 scales Q; z==2 writes V transposed)
    gemm_kernel<128, 64, EPI_BIAS, true><<<dim3(4, 64, 3), 256, 0, stream>>>(
        hb, wqkv + wofs, bqkv + l * 256, qb, vtb, 8192, 256, 256);
    attn_kernel<<<dim3(16, 64), 256, 0, stream>>>(qb, kbuf, vtb, ctxb);
    // fused O-proj + residual(hb) + LN1 -> attnb (grid 512, 2 blocks/CU)
    gemmln_kernel<256, false><<<512, 256, 0, stream>>>(
        ctxb, wo + wofs, o_b + l * 256, hb, ln1_g + l * 256, ln1_b + l * 256,
        attnb, nullptr, nullptr, nullptr);
    gemm_kernel<128, 128, EPI_GELU, false><<<dim3(8, 64), 256, 0, stream>>>(
        attnb, wf1 + fofs, f1_b + l * 1024, ffb, nullptr, 8192, 1024, 256);
    // fused FFN2 + residual(attnb) + LN2 -> hb (last layer: + head -> out)
    if (l < 3) {
      gemmln_kernel<1024, false><<<512, 256, 0, stream>>>(
          ffb, wf2 + fofs, f2_b + l * 256, attnb, ln2_g + l * 256,
          ln2_b + l * 256, hb, nullptr, nullptr, nullptr);
    } else {
      gemmln_kernel<1024, true><<<512, 256, 0, stream>>>(
          ffb, wf2 + fofs, f2_b + l * 256, attnb, ln2_g + l * 256,
          ln2_b + l * 256, hb, out_w, out_b, out);
    }
  }
}

// Round 9
// 369.570 us; speedup vs baseline: 1.0893x; 1.0318x over previous
//
#include <hip/hip_runtime.h>
#include <cstdint>
#include <cstddef>

// Problem: L=4, B=8, S=1024, D=256, H=8, DH=32, I=1024, M=4. bf16 MFMA compute.
#define SS 1024
#define DD 256

typedef unsigned short u16;
typedef __bf16 bf16x8 __attribute__((ext_vector_type(8)));
typedef float f32x4 __attribute__((ext_vector_type(4)));
typedef unsigned short us4 __attribute__((ext_vector_type(4)));

typedef __attribute__((address_space(3))) void lds_void_t;
typedef __attribute__((address_space(1))) const void gvoid_t;

__device__ __forceinline__ u16 f2bf(float f) {
  unsigned u = __builtin_bit_cast(unsigned, f);
  u += 0x7fffu + ((u >> 16) & 1u);     // RNE
  return (u16)(u >> 16);
}
__device__ __forceinline__ float bf2f(u16 h) {
  return __builtin_bit_cast(float, ((unsigned)h) << 16);
}
// pack two floats -> two bf16 (round-half-away, matches prior f2bf_fast)
__device__ __forceinline__ unsigned pack2bf(float a, float b) {
  unsigned ua = __builtin_bit_cast(unsigned, a) + 0x8000u;
  unsigned ub = __builtin_bit_cast(unsigned, b) + 0x8000u;
  return (ua >> 16) | (ub & 0xffff0000u);
}
// async global->LDS, 16B per lane; LDS dest must be wave-uniform base + lane*16
__device__ __forceinline__ void gld_lds16(const void* g, void* l) {
  __builtin_amdgcn_global_load_lds((gvoid_t*)g, (lds_void_t*)l, 16, 0, 0);
}
// DPP cross-lane within 16-lane rows (VALU-pipe, avoids LDS-pipe shuffles)
template <int CTRL>
__device__ __forceinline__ float dppf(float x) {
  int i = __builtin_bit_cast(int, x);
  int r = __builtin_amdgcn_update_dpp(i, i, CTRL, 0xf, 0xf, false);
  return __builtin_bit_cast(float, r);
}
__device__ __forceinline__ float row_sum16(float v) {
  v += dppf<0x121>(v);
  v += dppf<0x122>(v);
  v += dppf<0x124>(v);
  v += dppf<0x128>(v);
  return v;
}
// tanh-form GELU (R4-validated: passed at absmax 0.0078): exp2-domain tanh
__device__ __forceinline__ float gelu_f(float x) {
  float x2 = x * x;
  float y = x * (0.7978845608028654f + 0.0356774081363f * x2);
  float e = exp2f(fminf(-2.8853900817779268f * y, 88.f));  // exp(-2y)
  float th = (1.f - e) * __builtin_amdgcn_rcpf(1.f + e);
  return 0.5f * x * (1.f + th);
}

// ------- weight/bias conversion (fp32 -> bf16 / fp32 copy) + embed fused ----
struct CvtArgs {
  const float* src[9];
  void* dst[9];
  int n4[9];   // number of float4 elements (multiple of 256)
  int bf[9];   // 1 = convert to bf16, 0 = fp32 copy
};

__global__ __launch_bounds__(256)
void cvt_kernel(CvtArgs a, const int* __restrict__ x,
                const float* __restrict__ emb, const float* __restrict__ pe,
                u16* __restrict__ h) {
  int g = blockIdx.y;
  if (g == 9) {   // embedding: h = emb_w[x] + pe
    int wave = threadIdx.x >> 6, lane = threadIdx.x & 63;
    int row = blockIdx.x * 4 + wave;          // 0..8191
    int s = row & (SS - 1);
    int tok = x[row];
    float4 e = *(const float4*)(emb + (size_t)tok * DD + lane * 4);
    float4 p = *(const float4*)(pe + (size_t)s * DD + lane * 4);
    us4 o; o.x = f2bf(e.x + p.x); o.y = f2bf(e.y + p.y);
    o.z = f2bf(e.z + p.z); o.w = f2bf(e.w + p.w);
    *(us4*)(h + (size_t)row * DD + lane * 4) = o;
    return;
  }
  int i = blockIdx.x * 256 + threadIdx.x;
  if (i >= a.n4[g]) return;                 // block-uniform (n4 % 256 == 0)
  float4 v = ((const float4*)a.src[g])[i];
  if (a.bf[g]) {
    us4 o; o.x = f2bf(v.x); o.y = f2bf(v.y); o.z = f2bf(v.z); o.w = f2bf(v.w);
    ((us4*)a.dst[g])[i] = o;
  } else {
    ((float4*)a.dst[g])[i] = v;
  }
}

// ---------------- GEMM: out = A[M,K] @ W[N,K]^T + bias (+epilogue) ----------
enum { EPI_BIAS = 0, EPI_GELU = 1 };

// Q pre-scale: fold (1/sqrt(DH)) * log2(e) into Q so attention scores are
// exp2-ready (allows max-free softmax in attn_kernel).
#define Q_SCALE (0.17677669529663689f * 1.4426950408889634f)

template <int BM, int BN, int EPI, bool QKV>
__global__ __launch_bounds__(256)
void gemm_kernel(const u16* __restrict__ A, const u16* __restrict__ W,
                 const float* __restrict__ bias, void* __restrict__ outp,
                 u16* __restrict__ vt_out, int M, int N, int K) {
  const int n0 = blockIdx.x * BN;
  const int m0 = blockIdx.y * BM;
  const int tid = threadIdx.x;
  const int lane = tid & 63;
  const int l15 = lane & 15;
  const int quad = lane >> 4;
  const int wave = tid >> 6;
  const int wrow = wave >> 1, wcol = wave & 1;
  constexpr int WN = BN / 2;
  constexpr int NT = WN / 16;

  const u16* Wp = W;
  const float* biasp = bias;
  u16* out16 = (u16*)outp;
  int zid = 0;
  if constexpr (QKV) {   // grid.z selects q/k/v: [3][L][D][D] weights, [3][L*D] bias
    zid = blockIdx.z;
    Wp += (size_t)zid * 262144;
    biasp += (size_t)zid * 1024;
    out16 += (size_t)zid * 2097152;
  }

  __shared__ __align__(16) u16 lds[(BM + BN) * 64];
  char* ldsA = (char*)lds;
  char* ldsB = (char*)lds + BM * 128;

  const f32x4 fzero = {0.f, 0.f, 0.f, 0.f};
  f32x4 acc[4][NT];
#pragma unroll
  for (int i = 0; i < 4; ++i)
#pragma unroll
    for (int j = 0; j < NT; ++j) acc[i][j] = fzero;

  for (int kb = 0; kb < K; kb += 64) {
    __syncthreads();
    // stage A tile [BM][64] bf16, chunk (row,slot) <- global chunk slot^(row&7)
#pragma unroll
    for (int r = 0; r < BM * 8 / 256; ++r) {
      int c = r * 256 + tid;
      int row = c >> 3, slot = c & 7;
      int gc = slot ^ (row & 7);
      gld_lds16((const char*)(A + (size_t)(m0 + row) * K + kb) + gc * 16,
                ldsA + c * 16);
    }
#pragma unroll
    for (int r = 0; r < BN * 8 / 256; ++r) {
      int c = r * 256 + tid;
      int row = c >> 3, slot = c & 7;
      int gc = slot ^ (row & 7);
      gld_lds16((const char*)(Wp + (size_t)(n0 + row) * K + kb) + gc * 16,
                ldsB + c * 16);
    }
    __syncthreads();
#pragma unroll
    for (int kk = 0; kk < 2; ++kk) {
      bf16x8 af[4], bfr[NT];
#pragma unroll
      for (int i = 0; i < 4; ++i) {
        int row = wrow * 64 + i * 16 + l15;
        int slot = (kk * 4 + quad) ^ (row & 7);
        af[i] = *(const bf16x8*)(ldsA + row * 128 + slot * 16);
      }
#pragma unroll
      for (int j = 0; j < NT; ++j) {
        int row = wcol * WN + j * 16 + l15;
        int slot = (kk * 4 + quad) ^ (row & 7);
        bfr[j] = *(const bf16x8*)(ldsB + row * 128 + slot * 16);
      }
#pragma unroll
      for (int i = 0; i < 4; ++i)
#pragma unroll
        for (int j = 0; j < NT; ++j)
          acc[i][j] = __builtin_amdgcn_mfma_f32_16x16x32_bf16(af[i], bfr[j],
                                                              acc[i][j], 0, 0, 0);
    }
  }
  // epilogue: C/D layout col=lane&15, row=quad*4+reg
  if (QKV && zid == 2) {
    // V output: write transposed Vt[b][h][d][s] (s contiguous), packed 4 rows
#pragma unroll
    for (int i = 0; i < 4; ++i) {
      int rbase = m0 + wrow * 64 + i * 16 + quad * 4;
      int bidx = rbase >> 10, s0 = rbase & 1023;
#pragma unroll
      for (int j = 0; j < NT; ++j) {
        int col = n0 + wcol * WN + j * 16 + l15;   // = h*32 + d
        float bj = biasp[col];
        us4 o;
        o.x = f2bf(acc[i][j][0] + bj);
        o.y = f2bf(acc[i][j][1] + bj);
        o.z = f2bf(acc[i][j][2] + bj);
        o.w = f2bf(acc[i][j][3] + bj);
        *(us4*)(vt_out + ((size_t)(bidx * 8 + (col >> 5)) * 32 + (col & 31)) * SS + s0) = o;
      }
    }
    return;
  }
  const float oscale = (QKV && zid == 0) ? Q_SCALE : 1.0f;
#pragma unroll
  for (int i = 0; i < 4; ++i) {
    int rbase = m0 + wrow * 64 + i * 16 + quad * 4;
#pragma unroll
    for (int j = 0; j < NT; ++j) {
      int col = n0 + wcol * WN + j * 16 + l15;
      float bj = biasp[col];
#pragma unroll
      for (int r = 0; r < 4; ++r) {
        size_t idx = (size_t)(rbase + r) * N + col;
        float v = acc[i][j][r] + bj;
        if constexpr (EPI == EPI_GELU) {
          out16[idx] = f2bf(gelu_f(v));
        } else {
          out16[idx] = f2bf(v * oscale);
        }
      }
    }
  }
}

// -------- fused GEMM + bias + residual + LayerNorm (full row, BN=N=256) -----
// BM=16 rows/block, grid 512 -> 2 blocks/CU so barrier drains of one block
// are hidden by the sibling (m114 lesson, R8-verified). LN: in-lane + DPP over
// l15, cross-wave via LDS. LAST: logits = LN(h) @ out_w^T + out_b (M=4) fused.
template <int K, bool LAST>
__global__ __launch_bounds__(256)
void gemmln_kernel(const u16* __restrict__ A, const u16* __restrict__ W,
                   const float* __restrict__ bias, const u16* __restrict__ res,
                   const float* __restrict__ g, const float* __restrict__ bta,
                   u16* __restrict__ out, const float* __restrict__ ow,
                   const float* __restrict__ obias, float* __restrict__ outp) {
  const int m0 = blockIdx.x * 16;
  const int tid = threadIdx.x;
  const int l15 = tid & 15;
  const int quad = (tid & 63) >> 4;
  const int wave = tid >> 6;

  __shared__ __align__(16) u16 lds[(16 + 256) * 64];   // 34 KB
  char* ldsA = (char*)lds;
  char* ldsB = (char*)lds + 16 * 128;

  const f32x4 fzero = {0.f, 0.f, 0.f, 0.f};
  f32x4 acc[4];
#pragma unroll
  for (int j = 0; j < 4; ++j) acc[j] = fzero;

  for (int kb = 0; kb < K; kb += 64) {
    __syncthreads();
    if (tid < 128) {                   // A: 16 rows x 8 chunks = 128
      int c = tid;
      int row = c >> 3, slot = c & 7;
      int gc = slot ^ (row & 7);
      gld_lds16((const char*)(A + (size_t)(m0 + row) * K + kb) + gc * 16,
                ldsA + c * 16);
    }
#pragma unroll
    for (int r = 0; r < 8; ++r) {      // B: 256 rows x 8 chunks = 2048
      int c = r * 256 + tid;
      int row = c >> 3, slot = c & 7;
      int gc = slot ^ (row & 7);
      gld_lds16((const char*)(W + (size_t)row * K + kb) + gc * 16,
                ldsB + c * 16);
    }
    __syncthreads();
#pragma unroll
    for (int kk = 0; kk < 2; ++kk) {
      bf16x8 af, bfr[4];
      {
        int row = l15;
        int slot = (kk * 4 + quad) ^ (row & 7);
        af = *(const bf16x8*)(ldsA + row * 128 + slot * 16);
      }
#pragma unroll
      for (int j = 0; j < 4; ++j) {
        int row = wave * 64 + j * 16 + l15;
        int slot = (kk * 4 + quad) ^ (row & 7);
        bfr[j] = *(const bf16x8*)(ldsB + row * 128 + slot * 16);
      }
#pragma unroll
      for (int j = 0; j < 4; ++j)
        acc[j] = __builtin_amdgcn_mfma_f32_16x16x32_bf16(af, bfr[j], acc[j], 0, 0, 0);
    }
  }
  // bias + residual, per-lane partial LN sums
  float sm[4], sq[4];
#pragma unroll
  for (int r = 0; r < 4; ++r) { sm[r] = 0.f; sq[r] = 0.f; }
#pragma unroll
  for (int j = 0; j < 4; ++j) {
    int col = wave * 64 + j * 16 + l15;
    float bj = bias[col];
#pragma unroll
    for (int r = 0; r < 4; ++r) {
      int grow = m0 + quad * 4 + r;
      float v = acc[j][r] + bj + bf2f(res[(size_t)grow * DD + col]);
      acc[j][r] = v;
      sm[r] += v;
      sq[r] += v * v;
    }
  }
#pragma unroll
  for (int r = 0; r < 4; ++r) {
    sm[r] = row_sum16(sm[r]);
    sq[r] = row_sum16(sq[r]);
  }
  __syncthreads();                       // staging LDS is dead; reuse for stats
  float* sred = (float*)lds;             // [wave][{sum[16], sumsq[16]}]
  if (l15 == 0) {
#pragma unroll
    for (int r = 0; r < 4; ++r) {
      int ri = quad * 4 + r;
      sred[wave * 32 + ri] = sm[r];
      sred[wave * 32 + 16 + ri] = sq[r];
    }
  }
  __syncthreads();
  float mean[4], rstd[4];
#pragma unroll
  for (int r = 0; r < 4; ++r) {
    int ri = quad * 4 + r;
    float S = sred[ri] + sred[32 + ri] + sred[64 + ri] + sred[96 + ri];
    float S2 = sred[16 + ri] + sred[48 + ri] + sred[80 + ri] + sred[112 + ri];
    float mu = S * (1.f / 256.f);
    mean[r] = mu;
    rstd[r] = rsqrtf(S2 * (1.f / 256.f) - mu * mu + 1e-12f);
  }
  if constexpr (!LAST) {
#pragma unroll
    for (int j = 0; j < 4; ++j) {
      int col = wave * 64 + j * 16 + l15;
      float gj = g[col], bj = bta[col];
#pragma unroll
      for (int r = 0; r < 4; ++r) {
        int grow = m0 + quad * 4 + r;
        float v = (acc[j][r] - mean[r]) * rstd[r] * gj + bj;
        out[(size_t)grow * DD + col] = f2bf(v);
      }
    }
  } else {
    // head fused: logits[row][m] = sum_col LN(h)[row][col] * ow[m][col] + obias[m]
    float lg[4][4];
#pragma unroll
    for (int r = 0; r < 4; ++r)
#pragma unroll
      for (int m = 0; m < 4; ++m) lg[r][m] = 0.f;
#pragma unroll
    for (int j = 0; j < 4; ++j) {
      int col = wave * 64 + j * 16 + l15;
      float gj = g[col], bj = bta[col];
      float wm[4];
#pragma unroll
      for (int m = 0; m < 4; ++m) wm[m] = ow[m * 256 + col];
#pragma unroll
      for (int r = 0; r < 4; ++r) {
        float v = (acc[j][r] - mean[r]) * rstd[r] * gj + bj;
#pragma unroll
        for (int m = 0; m < 4; ++m) lg[r][m] += v * wm[m];
      }
    }
#pragma unroll
    for (int r = 0; r < 4; ++r)
#pragma unroll
      for (int m = 0; m < 4; ++m) lg[r][m] = row_sum16(lg[r][m]);
    __syncthreads();   // all waves done reading LN stats; reuse lds again
    float* sredh = (float*)lds;
    if (l15 == 0) {
#pragma unroll
      for (int r = 0; r < 4; ++r)
#pragma unroll
        for (int m = 0; m < 4; ++m)
          sredh[wave * 64 + (quad * 4 + r) * 4 + m] = lg[r][m];
    }
    __syncthreads();
    if (tid < 64) {
      int rr = tid >> 2, m = tid & 3;
      float s = sredh[rr * 4 + m] + sredh[64 + rr * 4 + m] +
                sredh[128 + rr * 4 + m] + sredh[192 + rr * 4 + m] + obias[m];
      outp[(size_t)(m0 + rr) * 4 + m] = s;
    }
  }
}

// ---------------- flash-style causal attention (max-free softmax) -----------
// Transposed-score variant: S^T = K·Q^T (operand swap, same frag loads) so
// each lane owns ONE q (=l15) and 4 consecutive keys per C reg group:
//  - P writes become 4x ds_write_b64 (was 16x ds_write_b16) — LDS-pipe relief
//  - PV computed as ctx^T = V^T·P^T via mfma(v, pf): pf/v loads unchanged
//  - l-sum: per-lane scalar + 2 shfl_xor (quads hold disjoint keys)
//  - ctx epilogue: 2 packed us4 stores (d consecutive in regs)
__global__ __launch_bounds__(256)
void attn_kernel(const u16* __restrict__ Q, const u16* __restrict__ Km,
                 const u16* __restrict__ Vt, u16* __restrict__ ctx) {
  const int tid = threadIdx.x;
  const int l15 = tid & 15;
  const int quad = (tid & 63) >> 4;
  const int wave = tid >> 6;
  const int y = blockIdx.y;
  const int qt = 15 - (((int)blockIdx.x + ((y >> 4) << 2)) & 15);  // long-first, CU-balanced
  const int q0 = qt * 64;
  const int b = y >> 3, h = y & 7;
  const int q0w = q0 + wave * 16;

  __shared__ __align__(16) u16 sK[2][64 * 40];   // [key][d] stride 40 u16
  __shared__ __align__(16) u16 sV[2][32 * 72];   // [d][key] stride 72 u16
  __shared__ __align__(16) u16 sP[4][16 * 72];   // per-wave [q][key] stride 72
  u16* sPw = sP[wave];

  bf16x8 qf = *(const bf16x8*)(Q + ((size_t)(b * SS + q0w + l15)) * DD + h * 32 + quad * 8);

  const int krow = tid >> 2, kch = tid & 3;   // K staging: 64 rows x 4 x 16B
  const int vd = tid >> 3, vch = tid & 7;     // V staging: 32 d x 8 x 16B
  const u16* Kbase = Km + (size_t)(b * SS) * DD + h * 32;
  const u16* Vbase = Vt + ((size_t)y * 32 + vd) * SS;

  uint4 kreg = *(const uint4*)(Kbase + (size_t)krow * DD + kch * 8);
  uint4 vreg = *(const uint4*)(Vbase + vch * 8);

  f32x4 o0 = {0.f, 0.f, 0.f, 0.f}, o1 = {0.f, 0.f, 0.f, 0.f};
  const f32x4 fzero = {0.f, 0.f, 0.f, 0.f};
  float rs = 0.f;                    // per-lane: q = q0w + l15, keys of my quads
  const int myq = q0w + l15;

  const int nt = q0 >> 6;
  for (int it = 0; it <= nt; ++it) {
    const int bsel = it & 1;
    *(uint4*)((char*)sK[bsel] + krow * 80 + kch * 16) = kreg;
    *(uint4*)((char*)sV[bsel] + vd * 144 + vch * 16) = vreg;
    if (it < nt) {
      int kb = (it + 1) * 64;
      kreg = *(const uint4*)(Kbase + (size_t)(kb + krow) * DD + kch * 8);
      vreg = *(const uint4*)(Vbase + kb + vch * 8);
    }
    __syncthreads();

    // S^T tiles: s4[t] = K_t · Q^T -> lane holds (keys t*16+quad*4+r, q=l15)
    f32x4 s4[4];
#pragma unroll
    for (int t = 0; t < 4; ++t) {
      bf16x8 kf = *(const bf16x8*)((const char*)sK[bsel] + (t * 16 + l15) * 80 + quad * 16);
      s4[t] = __builtin_amdgcn_mfma_f32_16x16x32_bf16(kf, qf, fzero, 0, 0, 0);
    }
    if (it == nt) {          // only the diagonal tile needs causal masking
#pragma unroll
      for (int t = 0; t < 4; ++t) {
        int kbase = it * 64 + t * 16 + quad * 4;
#pragma unroll
        for (int r = 0; r < 4; ++r) {
          float p = exp2f(s4[t][r]);
          p = (kbase + r > myq) ? 0.f : p;
          s4[t][r] = p;
          rs += p;
        }
      }
    } else {
#pragma unroll
      for (int t = 0; t < 4; ++t)
#pragma unroll
        for (int r = 0; r < 4; ++r) {
          float p = exp2f(s4[t][r]);
          s4[t][r] = p;
          rs += p;
        }
    }
    // P -> LDS [q=l15][key]: 4 consecutive keys per reg group -> b64 writes
#pragma unroll
    for (int t = 0; t < 4; ++t) {
      uint2 pk;
      pk.x = pack2bf(s4[t][0], s4[t][1]);
      pk.y = pack2bf(s4[t][2], s4[t][3]);
      *(uint2*)((char*)sPw + l15 * 144 + t * 32 + quad * 8) = pk;
    }
    // PV as ctx^T = V^T·P^T : A=v (m=d), B=pf (n=q) — loads unchanged
#pragma unroll
    for (int kt = 0; kt < 2; ++kt) {
      bf16x8 pf = *(const bf16x8*)((char*)sPw + l15 * 144 + kt * 64 + quad * 16);
      bf16x8 v0 = *(const bf16x8*)((const char*)sV[bsel] + l15 * 144 + kt * 64 + quad * 16);
      bf16x8 v1 = *(const bf16x8*)((const char*)sV[bsel] + (16 + l15) * 144 + kt * 64 + quad * 16);
      o0 = __builtin_amdgcn_mfma_f32_16x16x32_bf16(v0, pf, o0, 0, 0, 0);
      o1 = __builtin_amdgcn_mfma_f32_16x16x32_bf16(v1, pf, o1, 0, 0, 0);
    }
  }
  // l-sum across quads (disjoint keys, same q), then packed ctx write:
  rs += __shfl_xor(rs, 16);
  rs += __shfl_xor(rs, 32);
  float inv = 1.0f / rs;
  // o0[r] = ctx^T[d=quad*4+r][q=myq], o1[r] = d=16+quad*4+r
  size_t base = ((size_t)(b * SS + myq)) * DD + h * 32;
  us4 w0, w1;
#pragma unroll
  for (int r = 0; r < 4; ++r) {
    ((u16*)&w0)[r] = f2bf(o0[r] * inv);
    ((u16*)&w1)[r] = f2bf(o1[r] * inv);
  }
  *(us4*)(ctx + base + quad * 4) = w0;
  *(us4*)(ctx + base + 16 + quad * 4) = w1;
}

// ---------------- launcher ---------------------------------------------------
extern "C" void kernel_launch(void* const* d_in, const int* in_sizes, int n_in,
                              void* d_out, int out_size, void* d_ws, size_t ws_size,
                              hipStream_t stream) {
  const int* x = (const int*)d_in[0];
  const float* emb_w = (const float*)d_in[1];
  const float* pe = (const float*)d_in[2];
  const float* q_w = (const float*)d_in[3];
  const float* q_b = (const float*)d_in[4];
  const float* k_w = (const float*)d_in[5];
  const float* k_b = (const float*)d_in[6];
  const float* v_w = (const float*)d_in[7];
  const float* v_b = (const float*)d_in[8];
  const float* o_w = (const float*)d_in[9];
  const float* o_b = (const float*)d_in[10];
  const float* ln1_g = (const float*)d_in[11];
  const float* ln1_b = (const float*)d_in[12];
  const float* f1_w = (const float*)d_in[13];
  const float* f1_b = (const float*)d_in[14];
  const float* f2_w = (const float*)d_in[15];
  const float* f2_b = (const float*)d_in[16];
  const float* ln2_g = (const float*)d_in[17];
  const float* ln2_b = (const float*)d_in[18];
  const float* out_w = (const float*)d_in[19];
  const float* out_b = (const float*)d_in[20];
  float* out = (float*)d_out;

  char* w = (char*)d_ws;
  const size_t MB = 1ull << 20;
  u16* hb    = (u16*)(w + 0 * MB);    // [8192,256] bf16
  u16* qb    = (u16*)(w + 4 * MB);
  u16* kbuf  = (u16*)(w + 8 * MB);
  u16* vtb   = (u16*)(w + 12 * MB);   // V transposed [64 bh][32 d][1024 s]
  u16* ctxb  = (u16*)(w + 16 * MB);
  u16* attnb = (u16*)(w + 20 * MB);
  u16* ffb   = (u16*)(w + 24 * MB);   // [8192,1024] bf16
  u16* wqkv  = (u16*)(w + 48 * MB);   // [3][L,256,256] bf16
  u16* wo    = (u16*)(w + 50 * MB);   // [L,256,256] bf16
  u16* wf1   = (u16*)(w + 51 * MB);   // [L,1024,256] bf16
  u16* wf2   = (u16*)(w + 53 * MB);   // [L,256,1024] bf16
  float* bqkv = (float*)(w + 55 * MB); // [3][L*256] f32

  CvtArgs ca;
  ca.src[0] = q_w;  ca.dst[0] = wqkv;            ca.n4[0] = 65536;  ca.bf[0] = 1;
  ca.src[1] = k_w;  ca.dst[1] = wqkv + 262144;   ca.n4[1] = 65536;  ca.bf[1] = 1;
  ca.src[2] = v_w;  ca.dst[2] = wqkv + 524288;   ca.n4[2] = 65536;  ca.bf[2] = 1;
  ca.src[3] = o_w;  ca.dst[3] = wo;              ca.n4[3] = 65536;  ca.bf[3] = 1;
  ca.src[4] = f1_w; ca.dst[4] = wf1;             ca.n4[4] = 262144; ca.bf[4] = 1;
  ca.src[5] = f2_w; ca.dst[5] = wf2;             ca.n4[5] = 262144; ca.bf[5] = 1;
  ca.src[6] = q_b;  ca.dst[6] = bqkv;            ca.n4[6] = 256;    ca.bf[6] = 0;
  ca.src[7] = k_b;  ca.dst[7] = bqkv + 1024;     ca.n4[7] = 256;    ca.bf[7] = 0;
  ca.src[8] = v_b;  ca.dst[8] = bqkv + 2048;     ca.n4[8] = 256;    ca.bf[8] = 0;
  // groups 0-8: weight cvt; group 9: embedding (fused, one dispatch)
  cvt_kernel<<<dim3(2048, 10), 256, 0, stream>>>(ca, x, emb_w, pe, hb);

  for (int l = 0; l < 4; ++l) {
    const size_t wofs = (size_t)l * 65536;   // D*D per layer
    const size_t fofs = (size_t)l * 262144;  // I*D per layer
    // fused QKV (grid.z picks q/k/v; z==0 scales Q; z==2 writes V transposed)
    gemm_kernel<128, 64, EPI_BIAS, true><<<dim3(4, 64, 3), 256, 0, stream>>>(
        hb, wqkv + wofs, bqkv + l * 256, qb, vtb, 8192, 256, 256);
    attn_kernel<<<dim3(16, 64), 256, 0, stream>>>(qb, kbuf, vtb, ctxb);
    // fused O-proj + residual(hb) + LN1 -> attnb (grid 512, 2 blocks/CU)
    gemmln_kernel<256, false><<<512, 256, 0, stream>>>(
        ctxb, wo + wofs, o_b + l * 256, hb, ln1_g + l * 256, ln1_b + l * 256,
        attnb, nullptr, nullptr, nullptr);
    // FFN1: BN=64 -> grid 1024, ~4 blocks/CU (R8 occupancy lesson)
    gemm_kernel<128, 64, EPI_GELU, false><<<dim3(16, 64), 256, 0, stream>>>(
        attnb, wf1 + fofs, f1_b + l * 1024, ffb, nullptr, 8192, 1024, 256);
    // fused FFN2 + residual(attnb) + LN2 -> hb (last layer: + head -> out)
    if (l < 3) {
      gemmln_kernel<1024, false><<<512, 256, 0, stream>>>(
          ffb, wf2 + fofs, f2_b + l * 256, attnb, ln2_g + l * 256,
          ln2_b + l * 256, hb, nullptr, nullptr, nullptr);
    } else {
      gemmln_kernel<1024, true><<<512, 256, 0, stream>>>(
          ffb, wf2 + fofs, f2_b + l * 256, attnb, ln2_g + l * 256,
          ln2_b + l * 256, hb, out_w, out_b, out);
    }
  }
}